// Round 17
// baseline (300.393 us; speedup 1.0000x reference)
//
#include <hip/hip_runtime.h>
#include <hip/hip_fp8.h>

typedef __attribute__((ext_vector_type(8))) short short8;
typedef __attribute__((ext_vector_type(4))) short bf16x4;
typedef __attribute__((ext_vector_type(4))) float f32x4;
typedef __attribute__((ext_vector_type(2))) long i64x2;

#define DEV __device__ __forceinline__

DEV unsigned short f2bf(float f) {
    unsigned int u = __builtin_bit_cast(unsigned int, f);
    u += 0x7fffu + ((u >> 16) & 1u);
    return (unsigned short)(u >> 16);
}

DEV unsigned char f2fp8(float f) {
    return __hip_fp8_e4m3(f).__x;
}

#define GLOAD16(gp, lp)                                                        \
    __builtin_amdgcn_global_load_lds(                                          \
        (const __attribute__((address_space(1))) void*)(gp),                   \
        (__attribute__((address_space(3))) void*)(lp), 16, 0, 0)

// pi within a 64-block: stored[16j+i]=log[8j+i], stored[16j+8+i]=log[32+8j+i]
DEV int pi64(int o) {
    return (o < 32) ? ((o >> 3) * 16 + (o & 7)) : (((o - 32) >> 3) * 16 + 8 + (o & 7));
}

// ---------------------------------------------------- prep (LN+convert, fp8) ----
// (unchanged, verified)
__global__ __launch_bounds__(256) void prep(
    const float* __restrict__ hidden, const float* __restrict__ inputs,
    const float* __restrict__ ln1w, const float* __restrict__ ln1b,
    const float* __restrict__ ln2w, const float* __restrict__ ln2b,
    const float* __restrict__ Wq, const float* __restrict__ Wk, const float* __restrict__ Wv,
    unsigned char* __restrict__ LNh8, unsigned char* __restrict__ LNx8,
    unsigned char* __restrict__ Wq8, unsigned char* __restrict__ Wk8, unsigned char* __restrict__ Wv8)
{
    if (blockIdx.x < 9216) {
        int row = blockIdx.x * 4 + (threadIdx.x >> 6);
        int lane = threadIdx.x & 63;
        const float *src, *wp, *bp; unsigned char* dst;
        if (row < 4096) { src = hidden + (size_t)row * 1024; wp = ln1w; bp = ln1b; dst = LNh8 + (size_t)row * 1024; }
        else { int r = row - 4096; src = inputs + (size_t)r * 1024; wp = ln2w; bp = ln2b; dst = LNx8 + (size_t)r * 1024; }

        f32x4 v[4];
        float s = 0.f, ss = 0.f;
#pragma unroll
        for (int i = 0; i < 4; ++i) {
            v[i] = *reinterpret_cast<const f32x4*>(src + lane * 16 + i * 4);
#pragma unroll
            for (int j = 0; j < 4; ++j) { s += v[i][j]; ss += v[i][j] * v[i][j]; }
        }
#pragma unroll
        for (int off = 32; off >= 1; off >>= 1) { s += __shfl_xor(s, off); ss += __shfl_xor(ss, off); }
        float mu = s * (1.f / 1024.f);
        float var = fmaxf(ss * (1.f / 1024.f) - mu * mu, 0.f);
        float rs = rsqrtf(var + 1e-5f);

        unsigned char by[16];
#pragma unroll
        for (int i = 0; i < 4; ++i) {
            f32x4 wv = *reinterpret_cast<const f32x4*>(wp + lane * 16 + i * 4);
            f32x4 bv = *reinterpret_cast<const f32x4*>(bp + lane * 16 + i * 4);
#pragma unroll
            for (int j = 0; j < 4; ++j)
                by[i * 4 + j] = f2fp8((v[i][j] - mu) * rs * wv[j] + bv[j]);
        }
        int o = (lane * 16) & 63;
        int s0 = (o < 32) ? 2 * o : 2 * (o - 32) + 8;
        unsigned char* base = dst + (lane >> 2) * 64;
        *reinterpret_cast<unsigned long long*>(base + s0)      = *reinterpret_cast<unsigned long long*>(&by[0]);
        *reinterpret_cast<unsigned long long*>(base + s0 + 16) = *reinterpret_cast<unsigned long long*>(&by[8]);
    } else {
        unsigned tid = (blockIdx.x - 9216) * 256 + threadIdx.x;
        int arr = tid >> 16;
        unsigned idx = tid & 65535u;
        const float* s = (arr == 0) ? Wq : (arr == 1) ? Wk : Wv;
        unsigned char* d = (arr == 0) ? Wq8 : (arr == 1) ? Wk8 : Wv8;
        unsigned char by[16];
#pragma unroll
        for (int i = 0; i < 4; ++i) {
            f32x4 a = *reinterpret_cast<const f32x4*>(s + (size_t)idx * 16 + i * 4);
#pragma unroll
            for (int j = 0; j < 4; ++j) by[i * 4 + j] = f2fp8(a[j] * 64.f);
        }
        int o = (idx & 3) * 16;
        int s0 = (o < 32) ? 2 * o : 2 * (o - 32) + 8;
        unsigned char* base = d + (size_t)(idx >> 2) * 64;
        *reinterpret_cast<unsigned long long*>(base + s0)      = *reinterpret_cast<unsigned long long*>(&by[0]);
        *reinterpret_cast<unsigned long long*>(base + s0 + 16) = *reinterpret_cast<unsigned long long*>(&by[8]);
    }
}

// --------------------- gemm256 (fp8 in, fp8 out; swizzled, B-hoisted) ----
// Main loop identical to round 16 (verified). Epilogues now emit fp8:
//  - K/Q (non-trans): columns stored with pi per 64-block (matches attn reads)
//  - V (trans): Vt8[b][h][d][kv] fp8, kv linear
__global__ __launch_bounds__(512, 2) void gemm256(
    const unsigned char* __restrict__ A8, const unsigned char* __restrict__ Ah8,
    const unsigned char* __restrict__ W8, const unsigned char* __restrict__ Wq8,
    const float* __restrict__ bk, const float* __restrict__ bv, const float* __restrict__ bq,
    unsigned char* __restrict__ Cn, unsigned char* __restrict__ Vt, unsigned char* __restrict__ Qm)
{
    __shared__ __align__(16) char smemc[65536];

    int t = threadIdx.x, lane = t & 63, w = t >> 6, g = lane >> 4, lr = lane & 15;
    int wr = w >> 2, wcn = w & 3;
    int R0 = wr * 128, C0 = wcn * 64;

    int id = blockIdx.x;
    int m0, n0, trans = 0;
    const unsigned char *Ab_, *Wb_;
    const float* bias;
    unsigned char* Cout;
    if (id < 1024) {
        int xcd = id & 7, ord = id >> 3;
        int mt = xcd * 16 + ord / 8;
        int nt = ord % 8;
        m0 = mt * 256; n0 = nt * 256;
        Ab_ = A8; Wb_ = W8;
        if (nt < 4) { bias = bk; Cout = Cn; }
        else        { bias = bv; Cout = Vt; trans = 1; }
    } else {
        int id2 = id - 1024;
        int mt = id2 & 15, nt = id2 >> 4;
        m0 = mt * 256; n0 = nt * 256;
        Ab_ = Ah8; Wb_ = Wq8;
        bias = bq; Cout = Qm;
    }

    const unsigned char* Ap = Ab_ + (size_t)m0 * 1024;
    const unsigned char* Wp = Wb_ + (size_t)n0 * 1024;

    f32x4 acc[8][4];
#pragma unroll
    for (int i = 0; i < 8; ++i)
#pragma unroll
        for (int j = 0; j < 4; ++j) acc[i][j] = (f32x4)0.f;

    int schunk = (t & 3) ^ ((t >> 3) & 3);
    auto STAGE1 = [&](int slot, int kt, int q) {
        const unsigned char* P = (q < 2) ? Ap : Wp;
        char* ldsb = smemc + ((q < 2) ? 0 : 32768) + slot * 16384 + (q & 1) * 8192;
        int r = (q & 1) * 128 + (t >> 2);
        const char* gp = (const char*)(P + (size_t)r * 1024 + kt * 64 + schunk * 16);
        GLOAD16(gp, ldsb + (t >> 2) * 64 + (t & 3) * 16);
    };

    STAGE1(0, 0, 0); STAGE1(0, 0, 1); STAGE1(0, 0, 2); STAGE1(0, 0, 3);
    asm volatile("s_waitcnt vmcnt(0)" ::: "memory");
    __builtin_amdgcn_s_barrier();

    int xr = (lr >> 1) & 3;
    int slA = (g ^ xr) * 16;

    for (int kt = 0; kt < 16; ++kt) {
        const int cs = kt & 1;
        const char* Ab = smemc + cs * 16384;
        const char* Bb = smemc + 32768 + cs * 16384;
        i64x2 af[4], bf[4];

#pragma unroll
        for (int a = 0; a < 4; ++a) {
            int r = R0 + a * 16 + lr;
            af[a] = *reinterpret_cast<const i64x2*>(Ab + r * 64 + slA);
        }
#pragma unroll
        for (int ni = 0; ni < 4; ++ni) {
            int r = C0 + ni * 16 + lr;
            bf[ni] = *reinterpret_cast<const i64x2*>(Bb + r * 64 + slA);
        }
        if (kt < 15) { STAGE1(cs ^ 1, kt + 1, 0); STAGE1(cs ^ 1, kt + 1, 1); }
        __builtin_amdgcn_sched_barrier(0);
        __builtin_amdgcn_s_barrier();
        asm volatile("s_waitcnt lgkmcnt(0)" ::: "memory");
        __builtin_amdgcn_sched_barrier(0);
        __builtin_amdgcn_s_setprio(1);
#pragma unroll
        for (int a = 0; a < 4; ++a)
#pragma unroll
            for (int ni = 0; ni < 4; ++ni) {
                acc[a][ni] = __builtin_amdgcn_mfma_f32_16x16x32_fp8_fp8(
                    af[a][0], bf[ni][0], acc[a][ni], 0, 0, 0);
                acc[a][ni] = __builtin_amdgcn_mfma_f32_16x16x32_fp8_fp8(
                    af[a][1], bf[ni][1], acc[a][ni], 0, 0, 0);
            }
        __builtin_amdgcn_s_setprio(0);
        __builtin_amdgcn_sched_barrier(0);
        __builtin_amdgcn_s_barrier();

#pragma unroll
        for (int a = 0; a < 4; ++a) {
            int r = R0 + 64 + a * 16 + lr;
            af[a] = *reinterpret_cast<const i64x2*>(Ab + r * 64 + slA);
        }
        if (kt < 15) { STAGE1(cs ^ 1, kt + 1, 2); STAGE1(cs ^ 1, kt + 1, 3); }
        __builtin_amdgcn_sched_barrier(0);
        __builtin_amdgcn_s_barrier();
        asm volatile("s_waitcnt lgkmcnt(0)" ::: "memory");
        __builtin_amdgcn_sched_barrier(0);
        __builtin_amdgcn_s_setprio(1);
#pragma unroll
        for (int a = 0; a < 4; ++a)
#pragma unroll
            for (int ni = 0; ni < 4; ++ni) {
                acc[4 + a][ni] = __builtin_amdgcn_mfma_f32_16x16x32_fp8_fp8(
                    af[a][0], bf[ni][0], acc[4 + a][ni], 0, 0, 0);
                acc[4 + a][ni] = __builtin_amdgcn_mfma_f32_16x16x32_fp8_fp8(
                    af[a][1], bf[ni][1], acc[4 + a][ni], 0, 0, 0);
            }
        __builtin_amdgcn_s_setprio(0);
        asm volatile("s_waitcnt vmcnt(0)" ::: "memory");
        __builtin_amdgcn_sched_barrier(0);
        __builtin_amdgcn_s_barrier();
    }
    __syncthreads();

    const float SC = 0.015625f;   // 1/64 (W scale)
    unsigned char* CtS8 = (unsigned char*)smemc;   // [64][272] bytes
    if (!trans) {
#pragma unroll
        for (int ch = 0; ch < 4; ++ch) {
            if (ch) __syncthreads();
            if (wr == (ch >> 1)) {
                int ma = (ch & 1) * 4;
#pragma unroll
                for (int ni = 0; ni < 4; ++ni) {
                    int c = C0 + ni * 16 + lr;
                    float bvv = bias[n0 + c];
                    int cc = (c & ~63) + pi64(c & 63);
#pragma unroll
                    for (int a = 0; a < 4; ++a)
#pragma unroll
                        for (int j = 0; j < 4; ++j)
                            CtS8[(a * 16 + g * 4 + j) * 272 + cc] = f2fp8(acc[ma + a][ni][j] * SC + bvv);
                }
            }
            __syncthreads();
#pragma unroll
            for (int it = 0; it < 2; ++it) {
                int u2 = it * 512 + t;
                int row = u2 >> 4, c16 = u2 & 15;
                *reinterpret_cast<f32x4*>(Cout + (size_t)(m0 + ch * 64 + row) * 1024 + n0 + c16 * 16) =
                    *reinterpret_cast<const f32x4*>(&CtS8[row * 272 + c16 * 16]);
            }
        }
    } else {
        int nt = n0 >> 8;
        int hbase = (nt - 4) * 2;
        int b = m0 >> 12, kv0 = m0 & 4095;
#pragma unroll
        for (int ch = 0; ch < 4; ++ch) {
            if (ch) __syncthreads();
            if (wcn == ch) {
#pragma unroll
                for (int ni = 0; ni < 4; ++ni) {
                    int dl = ni * 16 + lr;
                    float bvv = bias[(nt - 4) * 256 + ch * 64 + dl];
#pragma unroll
                    for (int mi = 0; mi < 8; ++mi)
#pragma unroll
                        for (int j = 0; j < 4; ++j)
                            CtS8[dl * 272 + R0 + mi * 16 + g * 4 + j] = f2fp8(acc[mi][ni][j] * SC + bvv);
                }
            }
            __syncthreads();
            int hh = hbase + (ch >> 1), dbase = (ch & 1) * 64;
            unsigned char* dst = Cout + ((size_t)(b * 8 + hh) * 128 + dbase) * 4096 + kv0;
#pragma unroll
            for (int it = 0; it < 2; ++it) {
                int u2 = it * 512 + t;
                int row = u2 >> 4, c16 = u2 & 15;
                *reinterpret_cast<f32x4*>(dst + (size_t)row * 4096 + c16 * 16) =
                    *reinterpret_cast<const f32x4*>(&CtS8[row * 272 + c16 * 16]);
            }
        }
    }
}

// ----------------------------------------------------- attention (fp8) ----
// Structure identical to verified round-16 kernel; all operands fp8:
// K tile [64][128B] (pi'd d, row-XOR<<4), V tile [128][64B] ((d&6)<<3 XOR),
// P [64][64B] fp8 ((lr&7)<<3 XOR). THR2=8 so P <= 256 < e4m3 max.
__global__ __launch_bounds__(256, 2) void attn_kernel(
    const unsigned char* __restrict__ Qm8, const unsigned char* __restrict__ Km8,
    const unsigned char* __restrict__ Vt8, const float* __restrict__ hidden,
    float* __restrict__ out)
{
    __shared__ __align__(16) unsigned char Kl[2][64 * 128];   // 8 KB each
    __shared__ __align__(16) unsigned char Vt[2][128 * 64];   // 8 KB each
    __shared__ __align__(16) unsigned char Pl[64 * 64];       // 4 KB

    int t = threadIdx.x, lane = t & 63, w = t >> 6, g = lane >> 4, lr = lane & 15;
    int id = blockIdx.x;
    int swz = (id & 7) * 64 + (id >> 3);
    int qt = swz & 7, h = (swz >> 3) & 7, b = swz >> 6;

    // Q: 128 pi'd fp8 per row -> 2 x 16B
    i64x2 qf[2];
    {
        const unsigned char* qp = Qm8 + (size_t)(b * 512 + qt * 64 + w * 16 + lr) * 1024 + h * 128;
        qf[0] = *reinterpret_cast<const i64x2*>(qp + g * 16);
        qf[1] = *reinterpret_cast<const i64x2*>(qp + 64 + g * 16);
    }
    asm volatile("s_waitcnt vmcnt(0)" ::: "memory");

    float m2 = 0.f;
    float l = 0.f;
    f32x4 oacc[8];
#pragma unroll
    for (int nf = 0; nf < 8; ++nf) oacc[nf] = (f32x4)0.f;

    const float SCALE = 0.08838834764831845f;
    const float LOG2E = 1.4426950408889634f;
    const float K1 = SCALE * LOG2E;
    const float THR2 = 8.0f;              // P <= 2^8 = 256 < 448 (e4m3 max)

    size_t kbase = (size_t)b * 4096 * 1024 + h * 128;
    size_t vbase = ((size_t)(b * 8 + h)) * 128 * 4096;

    auto STAGE_K = [&](int buf, int c) {
        int kv0 = c * 64;
#pragma unroll
        for (int i = 0; i < 2; ++i) {
            int rb = w * 16 + i * 8;
            int row = rb + (lane >> 3);
            int cb = ((lane & 7) ^ (row & 7)) * 16;
            const unsigned char* gp = Km8 + kbase + (size_t)(kv0 + row) * 1024 + cb;
            GLOAD16(gp, &Kl[buf][rb * 128]);
        }
    };
    auto STAGE_V = [&](int buf, int c) {
        int kv0 = c * 64;
#pragma unroll
        for (int i = 0; i < 2; ++i) {
            int db = w * 32 + i * 16;
            int d = db + (lane >> 2);
            int cb = ((lane & 3) ^ ((d >> 1) & 3)) * 16;
            const unsigned char* gp = Vt8 + vbase + (size_t)d * 4096 + kv0 + cb;
            GLOAD16(gp, &Vt[buf][db * 64]);
        }
    };

    STAGE_K(0, 0); STAGE_V(0, 0);

    int rsw8 = (lr & 7) << 3;

    for (int c = 0; c < 64; ++c) {
        int cur = c & 1;
        asm volatile("s_waitcnt vmcnt(0) lgkmcnt(0)" ::: "memory");
        __builtin_amdgcn_sched_barrier(0);
        __builtin_amdgcn_s_barrier();
        if (c < 63) { STAGE_K(cur ^ 1, c + 1); STAGE_V(cur ^ 1, c + 1); }

        // S^T = K * Q^T (fp8): sacc[nf][j] = S[q=lr][kv=nf*16+g*4+j]
        f32x4 sacc[4];
#pragma unroll
        for (int nf = 0; nf < 4; ++nf) sacc[nf] = (f32x4)0.f;
#pragma unroll
        for (int kk2 = 0; kk2 < 2; ++kk2) {
            i64x2 kf[4];
#pragma unroll
            for (int nf = 0; nf < 4; ++nf) {
                int row = nf * 16 + lr;
                kf[nf] = *reinterpret_cast<const i64x2*>(
                    &Kl[cur][row * 128 + ((kk2 * 64 + g * 16) ^ ((row & 7) << 4))]);
            }
            __builtin_amdgcn_s_setprio(1);
#pragma unroll
            for (int nf = 0; nf < 4; ++nf) {
                sacc[nf] = __builtin_amdgcn_mfma_f32_16x16x32_fp8_fp8(kf[nf][0], qf[kk2][0], sacc[nf], 0, 0, 0);
                sacc[nf] = __builtin_amdgcn_mfma_f32_16x16x32_fp8_fp8(kf[nf][1], qf[kk2][1], sacc[nf], 0, 0, 0);
            }
            __builtin_amdgcn_s_setprio(0);
        }

        float smax = sacc[0][0];
#pragma unroll
        for (int nf = 0; nf < 4; ++nf)
#pragma unroll
            for (int j = 0; j < 4; ++j) smax = fmaxf(smax, sacc[nf][j]);
        float s2max = smax * K1;
        if (!__all(s2max <= m2 + THR2)) {
            float rm = s2max;
            rm = fmaxf(rm, __shfl_xor(rm, 16));
            rm = fmaxf(rm, __shfl_xor(rm, 32));
            float m2n = fmaxf(m2, rm);
            float corr = exp2f(m2 - m2n);
            l *= corr;
            m2 = m2n;
#pragma unroll
            for (int j = 0; j < 4; ++j) {
                float cj = __shfl(corr, g * 4 + j);
#pragma unroll
                for (int nf = 0; nf < 8; ++nf) oacc[nf][j] *= cj;
            }
        }
        int prow = w * 16 + lr;
#pragma unroll
        for (int nf = 0; nf < 4; ++nf) {
            float p0 = exp2f(sacc[nf][0] * K1 - m2);
            float p1 = exp2f(sacc[nf][1] * K1 - m2);
            float p2 = exp2f(sacc[nf][2] * K1 - m2);
            float p3 = exp2f(sacc[nf][3] * K1 - m2);
            l += (p0 + p1) + (p2 + p3);
            unsigned pk = (unsigned)f2fp8(p0) | ((unsigned)f2fp8(p1) << 8) |
                          ((unsigned)f2fp8(p2) << 16) | ((unsigned)f2fp8(p3) << 24);
            int pos = nf * 16 + g * 4;
            *reinterpret_cast<unsigned*>(
                &Pl[prow * 64 + ((pos & 0x38) ^ rsw8) + (pos & 7)]) = pk;
        }
        asm volatile("s_waitcnt lgkmcnt(0)" ::: "memory");
        __builtin_amdgcn_sched_barrier(0);

        // O += P * V^T (fp8)
#pragma unroll
        for (int kp = 0; kp < 2; ++kp) {
            long pa = *reinterpret_cast<const long*>(
                &Pl[prow * 64 + ((kp * 32 + g * 8) ^ rsw8)]);
#pragma unroll
            for (int nf = 0; nf < 8; ++nf) {
                int d = nf * 16 + lr;
                long vb = *reinterpret_cast<const long*>(
                    &Vt[cur][d * 64 + ((kp * 32 + g * 8) ^ ((d & 6) << 3))]);
                oacc[nf] = __builtin_amdgcn_mfma_f32_16x16x32_fp8_fp8(pa, vb, oacc[nf], 0, 0, 0);
            }
        }
    }

    l += __shfl_xor(l, 16);
    l += __shfl_xor(l, 32);
#pragma unroll
    for (int j = 0; j < 4; ++j) {
        float lj = __shfl(l, g * 4 + j);
        float inv = 1.f / lj;
        int q = qt * 64 + w * 16 + g * 4 + j;
        size_t base = (size_t)(b * 512 + q) * 1024 + h * 128;
#pragma unroll
        for (int nf = 0; nf < 8; ++nf) {
            int d = nf * 16 + lr;
            out[base + d] = hidden[base + d] + oacc[nf][j] * inv;
        }
    }
}

// ---------------------------------------------------------------- host ----
extern "C" void kernel_launch(void* const* d_in, const int* in_sizes, int n_in,
                              void* d_out, int out_size, void* d_ws, size_t ws_size,
                              hipStream_t stream) {
    const float* hidden = (const float*)d_in[0];
    const float* inputs = (const float*)d_in[1];
    const float* ln1w   = (const float*)d_in[2];
    const float* ln1b   = (const float*)d_in[3];
    const float* ln2w   = (const float*)d_in[4];
    const float* ln2b   = (const float*)d_in[5];
    const float* Wq     = (const float*)d_in[6];
    const float* bq     = (const float*)d_in[7];
    const float* Wk     = (const float*)d_in[8];
    const float* bk     = (const float*)d_in[9];
    const float* Wv     = (const float*)d_in[10];
    const float* bv     = (const float*)d_in[11];
    float* out = (float*)d_out;
    char* ws = (char*)d_ws;

    unsigned char* LNh8 = (unsigned char*)ws;          // 4096x1024 fp8
    unsigned char* LNx8 = LNh8 + 4194304;              // 32768x1024 fp8
    unsigned char* Wq8  = LNx8 + 33554432;
    unsigned char* Wk8  = Wq8 + 1048576;
    unsigned char* Wv8  = Wk8 + 1048576;
    unsigned char* Qm8  = Wv8 + 1048576;               // 4096x1024 fp8 (pi'd d)
    unsigned char* Km8  = Qm8 + 4194304;               // 32768x1024 fp8 (pi'd d)
    unsigned char* Vt8  = Km8 + 33554432;              // [b][h][128 d][4096 kv] fp8

    prep<<<dim3(9984), dim3(256), 0, stream>>>(
        hidden, inputs, ln1w, ln1b, ln2w, ln2b, Wq, Wk, Wv, LNh8, LNx8, Wq8, Wk8, Wv8);
    gemm256<<<dim3(1088), dim3(512), 0, stream>>>(
        LNx8, LNh8, Wk8, Wq8, bk, bv, bq, Km8, Vt8, Qm8);
    attn_kernel<<<dim3(512), dim3(256), 0, stream>>>(Qm8, Km8, Vt8, hidden, out);
}

// Round 18
// 265.256 us; speedup vs baseline: 1.1325x; 1.1325x over previous
//
#include <hip/hip_runtime.h>

typedef __attribute__((ext_vector_type(8))) short short8;
typedef __attribute__((ext_vector_type(4))) float f32x4;
typedef __attribute__((ext_vector_type(2))) long i64x2;

#define DEV __device__ __forceinline__

DEV unsigned short f2bf(float f) {
    unsigned int u = __builtin_bit_cast(unsigned int, f);
    u += 0x7fffu + ((u >> 16) & 1u);
    return (unsigned short)(u >> 16);
}

// 4 floats -> 4 packed OCP e4m3 bytes via v_cvt_pk_fp8_f32 (HW, saturating)
DEV unsigned cvt4fp8(float a, float b, float c, float d) {
    int w = __builtin_amdgcn_cvt_pk_fp8_f32(a, b, 0, false);
    w = __builtin_amdgcn_cvt_pk_fp8_f32(c, d, w, true);
    return (unsigned)w;
}

#define GLOAD16(gp, lp)                                                        \
    __builtin_amdgcn_global_load_lds(                                          \
        (const __attribute__((address_space(1))) void*)(gp),                   \
        (__attribute__((address_space(3))) void*)(lp), 16, 0, 0)

// pi within a 64-block: stored[16j+i]=log[8j+i], stored[16j+8+i]=log[32+8j+i]
DEV int pi64(int o) {
    return (o < 32) ? ((o >> 3) * 16 + (o & 7)) : (((o - 32) >> 3) * 16 + 8 + (o & 7));
}

// ---------------------------------------------------- prep (LN+convert, fp8) ----
__global__ __launch_bounds__(256) void prep(
    const float* __restrict__ hidden, const float* __restrict__ inputs,
    const float* __restrict__ ln1w, const float* __restrict__ ln1b,
    const float* __restrict__ ln2w, const float* __restrict__ ln2b,
    const float* __restrict__ Wq, const float* __restrict__ Wk, const float* __restrict__ Wv,
    unsigned char* __restrict__ LNh8, unsigned char* __restrict__ LNx8,
    unsigned char* __restrict__ Wq8, unsigned char* __restrict__ Wk8, unsigned char* __restrict__ Wv8)
{
    if (blockIdx.x < 9216) {
        int row = blockIdx.x * 4 + (threadIdx.x >> 6);
        int lane = threadIdx.x & 63;
        const float *src, *wp, *bp; unsigned char* dst;
        if (row < 4096) { src = hidden + (size_t)row * 1024; wp = ln1w; bp = ln1b; dst = LNh8 + (size_t)row * 1024; }
        else { int r = row - 4096; src = inputs + (size_t)r * 1024; wp = ln2w; bp = ln2b; dst = LNx8 + (size_t)r * 1024; }

        f32x4 v[4];
        float s = 0.f, ss = 0.f;
#pragma unroll
        for (int i = 0; i < 4; ++i) {
            v[i] = *reinterpret_cast<const f32x4*>(src + lane * 16 + i * 4);
#pragma unroll
            for (int j = 0; j < 4; ++j) { s += v[i][j]; ss += v[i][j] * v[i][j]; }
        }
#pragma unroll
        for (int off = 32; off >= 1; off >>= 1) { s += __shfl_xor(s, off); ss += __shfl_xor(ss, off); }
        float mu = s * (1.f / 1024.f);
        float var = fmaxf(ss * (1.f / 1024.f) - mu * mu, 0.f);
        float rs = rsqrtf(var + 1e-5f);

        unsigned ww[4];
#pragma unroll
        for (int i = 0; i < 4; ++i) {
            f32x4 wv = *reinterpret_cast<const f32x4*>(wp + lane * 16 + i * 4);
            f32x4 bv = *reinterpret_cast<const f32x4*>(bp + lane * 16 + i * 4);
            f32x4 o;
#pragma unroll
            for (int j = 0; j < 4; ++j) o[j] = (v[i][j] - mu) * rs * wv[j] + bv[j];
            ww[i] = cvt4fp8(o[0], o[1], o[2], o[3]);
        }
        int o = (lane * 16) & 63;
        int s0 = (o < 32) ? 2 * o : 2 * (o - 32) + 8;
        unsigned char* base = dst + (lane >> 2) * 64;
        *reinterpret_cast<unsigned long long*>(base + s0) =
            (unsigned long long)ww[0] | ((unsigned long long)ww[1] << 32);
        *reinterpret_cast<unsigned long long*>(base + s0 + 16) =
            (unsigned long long)ww[2] | ((unsigned long long)ww[3] << 32);
    } else {
        unsigned tid = (blockIdx.x - 9216) * 256 + threadIdx.x;
        int arr = tid >> 16;
        unsigned idx = tid & 65535u;
        const float* s = (arr == 0) ? Wq : (arr == 1) ? Wk : Wv;
        unsigned char* d = (arr == 0) ? Wq8 : (arr == 1) ? Wk8 : Wv8;
        unsigned ww[4];
#pragma unroll
        for (int i = 0; i < 4; ++i) {
            f32x4 a = *reinterpret_cast<const f32x4*>(s + (size_t)idx * 16 + i * 4);
            ww[i] = cvt4fp8(a[0] * 64.f, a[1] * 64.f, a[2] * 64.f, a[3] * 64.f);
        }
        int o = (idx & 3) * 16;
        int s0 = (o < 32) ? 2 * o : 2 * (o - 32) + 8;
        unsigned char* base = d + (size_t)(idx >> 2) * 64;
        *reinterpret_cast<unsigned long long*>(base + s0) =
            (unsigned long long)ww[0] | ((unsigned long long)ww[1] << 32);
        *reinterpret_cast<unsigned long long*>(base + s0 + 16) =
            (unsigned long long)ww[2] | ((unsigned long long)ww[3] << 32);
    }
}

// --------------------- gemm256 (fp8 in, fp8 out; HW cvt epilogues) ----
__global__ __launch_bounds__(512, 2) void gemm256(
    const unsigned char* __restrict__ A8, const unsigned char* __restrict__ Ah8,
    const unsigned char* __restrict__ W8, const unsigned char* __restrict__ Wq8,
    const float* __restrict__ bk, const float* __restrict__ bv, const float* __restrict__ bq,
    unsigned char* __restrict__ Cn, unsigned char* __restrict__ Vt, unsigned char* __restrict__ Qm)
{
    __shared__ __align__(16) char smemc[65536];

    int t = threadIdx.x, lane = t & 63, w = t >> 6, g = lane >> 4, lr = lane & 15;
    int wr = w >> 2, wcn = w & 3;
    int R0 = wr * 128, C0 = wcn * 64;

    int id = blockIdx.x;
    int m0, n0, trans = 0;
    const unsigned char *Ab_, *Wb_;
    const float* bias;
    unsigned char* Cout;
    if (id < 1024) {
        int xcd = id & 7, ord = id >> 3;
        int mt = xcd * 16 + ord / 8;
        int nt = ord % 8;
        m0 = mt * 256; n0 = nt * 256;
        Ab_ = A8; Wb_ = W8;
        if (nt < 4) { bias = bk; Cout = Cn; }
        else        { bias = bv; Cout = Vt; trans = 1; }
    } else {
        int id2 = id - 1024;
        int mt = id2 & 15, nt = id2 >> 4;
        m0 = mt * 256; n0 = nt * 256;
        Ab_ = Ah8; Wb_ = Wq8;
        bias = bq; Cout = Qm;
    }

    const unsigned char* Ap = Ab_ + (size_t)m0 * 1024;
    const unsigned char* Wp = Wb_ + (size_t)n0 * 1024;

    f32x4 acc[8][4];
#pragma unroll
    for (int i = 0; i < 8; ++i)
#pragma unroll
        for (int j = 0; j < 4; ++j) acc[i][j] = (f32x4)0.f;

    int schunk = (t & 3) ^ ((t >> 3) & 3);
    auto STAGE1 = [&](int slot, int kt, int q) {
        const unsigned char* P = (q < 2) ? Ap : Wp;
        char* ldsb = smemc + ((q < 2) ? 0 : 32768) + slot * 16384 + (q & 1) * 8192;
        int r = (q & 1) * 128 + (t >> 2);
        const char* gp = (const char*)(P + (size_t)r * 1024 + kt * 64 + schunk * 16);
        GLOAD16(gp, ldsb + (t >> 2) * 64 + (t & 3) * 16);
    };

    STAGE1(0, 0, 0); STAGE1(0, 0, 1); STAGE1(0, 0, 2); STAGE1(0, 0, 3);
    asm volatile("s_waitcnt vmcnt(0)" ::: "memory");
    __builtin_amdgcn_s_barrier();

    int xr = (lr >> 1) & 3;
    int slA = (g ^ xr) * 16;

    for (int kt = 0; kt < 16; ++kt) {
        const int cs = kt & 1;
        const char* Ab = smemc + cs * 16384;
        const char* Bb = smemc + 32768 + cs * 16384;
        i64x2 af[4], bf[4];

#pragma unroll
        for (int a = 0; a < 4; ++a) {
            int r = R0 + a * 16 + lr;
            af[a] = *reinterpret_cast<const i64x2*>(Ab + r * 64 + slA);
        }
#pragma unroll
        for (int ni = 0; ni < 4; ++ni) {
            int r = C0 + ni * 16 + lr;
            bf[ni] = *reinterpret_cast<const i64x2*>(Bb + r * 64 + slA);
        }
        if (kt < 15) { STAGE1(cs ^ 1, kt + 1, 0); STAGE1(cs ^ 1, kt + 1, 1); }
        __builtin_amdgcn_sched_barrier(0);
        __builtin_amdgcn_s_barrier();
        asm volatile("s_waitcnt lgkmcnt(0)" ::: "memory");
        __builtin_amdgcn_sched_barrier(0);
        __builtin_amdgcn_s_setprio(1);
#pragma unroll
        for (int a = 0; a < 4; ++a)
#pragma unroll
            for (int ni = 0; ni < 4; ++ni) {
                acc[a][ni] = __builtin_amdgcn_mfma_f32_16x16x32_fp8_fp8(
                    af[a][0], bf[ni][0], acc[a][ni], 0, 0, 0);
                acc[a][ni] = __builtin_amdgcn_mfma_f32_16x16x32_fp8_fp8(
                    af[a][1], bf[ni][1], acc[a][ni], 0, 0, 0);
            }
        __builtin_amdgcn_s_setprio(0);
        __builtin_amdgcn_sched_barrier(0);
        __builtin_amdgcn_s_barrier();

#pragma unroll
        for (int a = 0; a < 4; ++a) {
            int r = R0 + 64 + a * 16 + lr;
            af[a] = *reinterpret_cast<const i64x2*>(Ab + r * 64 + slA);
        }
        if (kt < 15) { STAGE1(cs ^ 1, kt + 1, 2); STAGE1(cs ^ 1, kt + 1, 3); }
        __builtin_amdgcn_sched_barrier(0);
        __builtin_amdgcn_s_barrier();
        asm volatile("s_waitcnt lgkmcnt(0)" ::: "memory");
        __builtin_amdgcn_sched_barrier(0);
        __builtin_amdgcn_s_setprio(1);
#pragma unroll
        for (int a = 0; a < 4; ++a)
#pragma unroll
            for (int ni = 0; ni < 4; ++ni) {
                acc[4 + a][ni] = __builtin_amdgcn_mfma_f32_16x16x32_fp8_fp8(
                    af[a][0], bf[ni][0], acc[4 + a][ni], 0, 0, 0);
                acc[4 + a][ni] = __builtin_amdgcn_mfma_f32_16x16x32_fp8_fp8(
                    af[a][1], bf[ni][1], acc[4 + a][ni], 0, 0, 0);
            }
        __builtin_amdgcn_s_setprio(0);
        asm volatile("s_waitcnt vmcnt(0)" ::: "memory");
        __builtin_amdgcn_sched_barrier(0);
        __builtin_amdgcn_s_barrier();
    }
    __syncthreads();

    const float SC = 0.015625f;   // 1/64 (W scale)
    unsigned char* CtS8 = (unsigned char*)smemc;   // [64][272] bytes
    if (!trans) {
#pragma unroll
        for (int ch = 0; ch < 4; ++ch) {
            if (ch) __syncthreads();
            if (wr == (ch >> 1)) {
                int ma = (ch & 1) * 4;
#pragma unroll
                for (int ni = 0; ni < 4; ++ni) {
                    int c = C0 + ni * 16 + lr;
                    float bvv = bias[n0 + c];
                    int cc = (c & ~63) + pi64(c & 63);
#pragma unroll
                    for (int a = 0; a < 4; ++a) {
                        unsigned wv = cvt4fp8(acc[ma + a][ni][0] * SC + bvv,
                                              acc[ma + a][ni][1] * SC + bvv,
                                              acc[ma + a][ni][2] * SC + bvv,
                                              acc[ma + a][ni][3] * SC + bvv);
#pragma unroll
                        for (int j = 0; j < 4; ++j)
                            CtS8[(a * 16 + g * 4 + j) * 272 + cc] =
                                (unsigned char)((wv >> (8 * j)) & 0xffu);
                    }
                }
            }
            __syncthreads();
#pragma unroll
            for (int it = 0; it < 2; ++it) {
                int u2 = it * 512 + t;
                int row = u2 >> 4, c16 = u2 & 15;
                *reinterpret_cast<f32x4*>(Cout + (size_t)(m0 + ch * 64 + row) * 1024 + n0 + c16 * 16) =
                    *reinterpret_cast<const f32x4*>(&CtS8[row * 272 + c16 * 16]);
            }
        }
    } else {
        int nt = n0 >> 8;
        int hbase = (nt - 4) * 2;
        int b = m0 >> 12, kv0 = m0 & 4095;
#pragma unroll
        for (int ch = 0; ch < 4; ++ch) {
            if (ch) __syncthreads();
            if (wcn == ch) {
#pragma unroll
                for (int ni = 0; ni < 4; ++ni) {
                    int dl = ni * 16 + lr;
                    float bvv = bias[(nt - 4) * 256 + ch * 64 + dl];
#pragma unroll
                    for (int mi = 0; mi < 8; ++mi) {
                        unsigned wv = cvt4fp8(acc[mi][ni][0] * SC + bvv,
                                              acc[mi][ni][1] * SC + bvv,
                                              acc[mi][ni][2] * SC + bvv,
                                              acc[mi][ni][3] * SC + bvv);
                        *reinterpret_cast<unsigned*>(
                            &CtS8[dl * 272 + R0 + mi * 16 + g * 4]) = wv;
                    }
                }
            }
            __syncthreads();
            int hh = hbase + (ch >> 1), dbase = (ch & 1) * 64;
            unsigned char* dst = Cout + ((size_t)(b * 8 + hh) * 128 + dbase) * 4096 + kv0;
#pragma unroll
            for (int it = 0; it < 2; ++it) {
                int u2 = it * 512 + t;
                int row = u2 >> 4, c16 = u2 & 15;
                *reinterpret_cast<f32x4*>(dst + (size_t)row * 4096 + c16 * 16) =
                    *reinterpret_cast<const f32x4*>(&CtS8[row * 272 + c16 * 16]);
            }
        }
    }
}

// ----------------------------------------------------- attention (fp8) ----
// round-17 structure; P conversion now 2x HW cvt_pk + one u32 store.
__global__ __launch_bounds__(256, 2) void attn_kernel(
    const unsigned char* __restrict__ Qm8, const unsigned char* __restrict__ Km8,
    const unsigned char* __restrict__ Vt8, const float* __restrict__ hidden,
    float* __restrict__ out)
{
    __shared__ __align__(16) unsigned char Kl[2][64 * 128];
    __shared__ __align__(16) unsigned char Vt[2][128 * 64];
    __shared__ __align__(16) unsigned char Pl[64 * 64];

    int t = threadIdx.x, lane = t & 63, w = t >> 6, g = lane >> 4, lr = lane & 15;
    int id = blockIdx.x;
    int swz = (id & 7) * 64 + (id >> 3);
    int qt = swz & 7, h = (swz >> 3) & 7, b = swz >> 6;

    i64x2 qf[2];
    {
        const unsigned char* qp = Qm8 + (size_t)(b * 512 + qt * 64 + w * 16 + lr) * 1024 + h * 128;
        qf[0] = *reinterpret_cast<const i64x2*>(qp + g * 16);
        qf[1] = *reinterpret_cast<const i64x2*>(qp + 64 + g * 16);
    }
    asm volatile("s_waitcnt vmcnt(0)" ::: "memory");

    float m2 = 0.f;
    float l = 0.f;
    f32x4 oacc[8];
#pragma unroll
    for (int nf = 0; nf < 8; ++nf) oacc[nf] = (f32x4)0.f;

    const float SCALE = 0.08838834764831845f;
    const float LOG2E = 1.4426950408889634f;
    const float K1 = SCALE * LOG2E;
    const float THR2 = 8.0f;

    size_t kbase = (size_t)b * 4096 * 1024 + h * 128;
    size_t vbase = ((size_t)(b * 8 + h)) * 128 * 4096;

    auto STAGE_K = [&](int buf, int c) {
        int kv0 = c * 64;
#pragma unroll
        for (int i = 0; i < 2; ++i) {
            int rb = w * 16 + i * 8;
            int row = rb + (lane >> 3);
            int cb = ((lane & 7) ^ (row & 7)) * 16;
            const unsigned char* gp = Km8 + kbase + (size_t)(kv0 + row) * 1024 + cb;
            GLOAD16(gp, &Kl[buf][rb * 128]);
        }
    };
    auto STAGE_V = [&](int buf, int c) {
        int kv0 = c * 64;
#pragma unroll
        for (int i = 0; i < 2; ++i) {
            int db = w * 32 + i * 16;
            int d = db + (lane >> 2);
            int cb = ((lane & 3) ^ ((d >> 1) & 3)) * 16;
            const unsigned char* gp = Vt8 + vbase + (size_t)d * 4096 + kv0 + cb;
            GLOAD16(gp, &Vt[buf][db * 64]);
        }
    };

    STAGE_K(0, 0); STAGE_V(0, 0);

    int rsw8 = (lr & 7) << 3;

    for (int c = 0; c < 64; ++c) {
        int cur = c & 1;
        asm volatile("s_waitcnt vmcnt(0) lgkmcnt(0)" ::: "memory");
        __builtin_amdgcn_sched_barrier(0);
        __builtin_amdgcn_s_barrier();
        if (c < 63) { STAGE_K(cur ^ 1, c + 1); STAGE_V(cur ^ 1, c + 1); }

        f32x4 sacc[4];
#pragma unroll
        for (int nf = 0; nf < 4; ++nf) sacc[nf] = (f32x4)0.f;
#pragma unroll
        for (int kk2 = 0; kk2 < 2; ++kk2) {
            i64x2 kf[4];
#pragma unroll
            for (int nf = 0; nf < 4; ++nf) {
                int row = nf * 16 + lr;
                kf[nf] = *reinterpret_cast<const i64x2*>(
                    &Kl[cur][row * 128 + ((kk2 * 64 + g * 16) ^ ((row & 7) << 4))]);
            }
            __builtin_amdgcn_s_setprio(1);
#pragma unroll
            for (int nf = 0; nf < 4; ++nf) {
                sacc[nf] = __builtin_amdgcn_mfma_f32_16x16x32_fp8_fp8(kf[nf][0], qf[kk2][0], sacc[nf], 0, 0, 0);
                sacc[nf] = __builtin_amdgcn_mfma_f32_16x16x32_fp8_fp8(kf[nf][1], qf[kk2][1], sacc[nf], 0, 0, 0);
            }
            __builtin_amdgcn_s_setprio(0);
        }

        float smax = sacc[0][0];
#pragma unroll
        for (int nf = 0; nf < 4; ++nf)
#pragma unroll
            for (int j = 0; j < 4; ++j) smax = fmaxf(smax, sacc[nf][j]);
        float s2max = smax * K1;
        if (!__all(s2max <= m2 + THR2)) {
            float rm = s2max;
            rm = fmaxf(rm, __shfl_xor(rm, 16));
            rm = fmaxf(rm, __shfl_xor(rm, 32));
            float m2n = fmaxf(m2, rm);
            float corr = exp2f(m2 - m2n);
            l *= corr;
            m2 = m2n;
#pragma unroll
            for (int j = 0; j < 4; ++j) {
                float cj = __shfl(corr, g * 4 + j);
#pragma unroll
                for (int nf = 0; nf < 8; ++nf) oacc[nf][j] *= cj;
            }
        }
        int prow = w * 16 + lr;
#pragma unroll
        for (int nf = 0; nf < 4; ++nf) {
            float p0 = exp2f(sacc[nf][0] * K1 - m2);
            float p1 = exp2f(sacc[nf][1] * K1 - m2);
            float p2 = exp2f(sacc[nf][2] * K1 - m2);
            float p3 = exp2f(sacc[nf][3] * K1 - m2);
            l += (p0 + p1) + (p2 + p3);
            unsigned pk = cvt4fp8(p0, p1, p2, p3);
            int pos = nf * 16 + g * 4;
            *reinterpret_cast<unsigned*>(
                &Pl[prow * 64 + ((pos & 0x38) ^ rsw8) + (pos & 7)]) = pk;
        }
        asm volatile("s_waitcnt lgkmcnt(0)" ::: "memory");
        __builtin_amdgcn_sched_barrier(0);

#pragma unroll
        for (int kp = 0; kp < 2; ++kp) {
            long pa = *reinterpret_cast<const long*>(
                &Pl[prow * 64 + ((kp * 32 + g * 8) ^ rsw8)]);
#pragma unroll
            for (int nf = 0; nf < 8; ++nf) {
                int d = nf * 16 + lr;
                long vb = *reinterpret_cast<const long*>(
                    &Vt[cur][d * 64 + ((kp * 32 + g * 8) ^ ((d & 6) << 3))]);
                oacc[nf] = __builtin_amdgcn_mfma_f32_16x16x32_fp8_fp8(pa, vb, oacc[nf], 0, 0, 0);
            }
        }
    }

    l += __shfl_xor(l, 16);
    l += __shfl_xor(l, 32);
#pragma unroll
    for (int j = 0; j < 4; ++j) {
        float lj = __shfl(l, g * 4 + j);
        float inv = 1.f / lj;
        int q = qt * 64 + w * 16 + g * 4 + j;
        size_t base = (size_t)(b * 512 + q) * 1024 + h * 128;
#pragma unroll
        for (int nf = 0; nf < 8; ++nf) {
            int d = nf * 16 + lr;
            out[base + d] = hidden[base + d] + oacc[nf][j] * inv;
        }
    }
}

// ---------------------------------------------------------------- host ----
extern "C" void kernel_launch(void* const* d_in, const int* in_sizes, int n_in,
                              void* d_out, int out_size, void* d_ws, size_t ws_size,
                              hipStream_t stream) {
    const float* hidden = (const float*)d_in[0];
    const float* inputs = (const float*)d_in[1];
    const float* ln1w   = (const float*)d_in[2];
    const float* ln1b   = (const float*)d_in[3];
    const float* ln2w   = (const float*)d_in[4];
    const float* ln2b   = (const float*)d_in[5];
    const float* Wq     = (const float*)d_in[6];
    const float* bq     = (const float*)d_in[7];
    const float* Wk     = (const float*)d_in[8];
    const float* bk     = (const float*)d_in[9];
    const float* Wv     = (const float*)d_in[10];
    const float* bv     = (const float*)d_in[11];
    float* out = (float*)d_out;
    char* ws = (char*)d_ws;

    unsigned char* LNh8 = (unsigned char*)ws;          // 4096x1024 fp8
    unsigned char* LNx8 = LNh8 + 4194304;              // 32768x1024 fp8
    unsigned char* Wq8  = LNx8 + 33554432;
    unsigned char* Wk8  = Wq8 + 1048576;
    unsigned char* Wv8  = Wk8 + 1048576;
    unsigned char* Qm8  = Wv8 + 1048576;               // 4096x1024 fp8 (pi'd d)
    unsigned char* Km8  = Qm8 + 4194304;               // 32768x1024 fp8 (pi'd d)
    unsigned char* Vt8  = Km8 + 33554432;              // [b][h][128 d][4096 kv] fp8

    prep<<<dim3(9984), dim3(256), 0, stream>>>(
        hidden, inputs, ln1w, ln1b, ln2w, ln2b, Wq, Wk, Wv, LNh8, LNx8, Wq8, Wk8, Wv8);
    gemm256<<<dim3(1088), dim3(512), 0, stream>>>(
        LNx8, LNh8, Wk8, Wq8, bk, bv, bq, Km8, Vt8, Qm8);
    attn_kernel<<<dim3(512), dim3(256), 0, stream>>>(Qm8, Km8, Vt8, hidden, out);
}

// Round 19
// 261.167 us; speedup vs baseline: 1.1502x; 1.0157x over previous
//
#include <hip/hip_runtime.h>

typedef __attribute__((ext_vector_type(8))) short short8;
typedef __attribute__((ext_vector_type(4))) float f32x4;
typedef __attribute__((ext_vector_type(2))) long i64x2;

#define DEV __device__ __forceinline__

DEV unsigned short f2bf(float f) {
    unsigned int u = __builtin_bit_cast(unsigned int, f);
    u += 0x7fffu + ((u >> 16) & 1u);
    return (unsigned short)(u >> 16);
}

// 4 floats -> 4 packed OCP e4m3 bytes via v_cvt_pk_fp8_f32 (HW, saturating)
DEV unsigned cvt4fp8(float a, float b, float c, float d) {
    int w = __builtin_amdgcn_cvt_pk_fp8_f32(a, b, 0, false);
    w = __builtin_amdgcn_cvt_pk_fp8_f32(c, d, w, true);
    return (unsigned)w;
}

#define GLOAD16(gp, lp)                                                        \
    __builtin_amdgcn_global_load_lds(                                          \
        (const __attribute__((address_space(1))) void*)(gp),                   \
        (__attribute__((address_space(3))) void*)(lp), 16, 0, 0)

// pi within a 64-block: stored[16j+i]=log[8j+i], stored[16j+8+i]=log[32+8j+i]
DEV int pi64(int o) {
    return (o < 32) ? ((o >> 3) * 16 + (o & 7)) : (((o - 32) >> 3) * 16 + 8 + (o & 7));
}

// ---------------------------------------------------- prep (LN+convert, fp8) ----
__global__ __launch_bounds__(256) void prep(
    const float* __restrict__ hidden, const float* __restrict__ inputs,
    const float* __restrict__ ln1w, const float* __restrict__ ln1b,
    const float* __restrict__ ln2w, const float* __restrict__ ln2b,
    const float* __restrict__ Wq, const float* __restrict__ Wk, const float* __restrict__ Wv,
    unsigned char* __restrict__ LNh8, unsigned char* __restrict__ LNx8,
    unsigned char* __restrict__ Wq8, unsigned char* __restrict__ Wk8, unsigned char* __restrict__ Wv8)
{
    if (blockIdx.x < 9216) {
        int row = blockIdx.x * 4 + (threadIdx.x >> 6);
        int lane = threadIdx.x & 63;
        const float *src, *wp, *bp; unsigned char* dst;
        if (row < 4096) { src = hidden + (size_t)row * 1024; wp = ln1w; bp = ln1b; dst = LNh8 + (size_t)row * 1024; }
        else { int r = row - 4096; src = inputs + (size_t)r * 1024; wp = ln2w; bp = ln2b; dst = LNx8 + (size_t)r * 1024; }

        f32x4 v[4];
        float s = 0.f, ss = 0.f;
#pragma unroll
        for (int i = 0; i < 4; ++i) {
            v[i] = *reinterpret_cast<const f32x4*>(src + lane * 16 + i * 4);
#pragma unroll
            for (int j = 0; j < 4; ++j) { s += v[i][j]; ss += v[i][j] * v[i][j]; }
        }
#pragma unroll
        for (int off = 32; off >= 1; off >>= 1) { s += __shfl_xor(s, off); ss += __shfl_xor(ss, off); }
        float mu = s * (1.f / 1024.f);
        float var = fmaxf(ss * (1.f / 1024.f) - mu * mu, 0.f);
        float rs = rsqrtf(var + 1e-5f);

        unsigned ww[4];
#pragma unroll
        for (int i = 0; i < 4; ++i) {
            f32x4 wv = *reinterpret_cast<const f32x4*>(wp + lane * 16 + i * 4);
            f32x4 bv = *reinterpret_cast<const f32x4*>(bp + lane * 16 + i * 4);
            f32x4 o;
#pragma unroll
            for (int j = 0; j < 4; ++j) o[j] = (v[i][j] - mu) * rs * wv[j] + bv[j];
            ww[i] = cvt4fp8(o[0], o[1], o[2], o[3]);
        }
        int o = (lane * 16) & 63;
        int s0 = (o < 32) ? 2 * o : 2 * (o - 32) + 8;
        unsigned char* base = dst + (lane >> 2) * 64;
        *reinterpret_cast<unsigned long long*>(base + s0) =
            (unsigned long long)ww[0] | ((unsigned long long)ww[1] << 32);
        *reinterpret_cast<unsigned long long*>(base + s0 + 16) =
            (unsigned long long)ww[2] | ((unsigned long long)ww[3] << 32);
    } else {
        unsigned tid = (blockIdx.x - 9216) * 256 + threadIdx.x;
        int arr = tid >> 16;
        unsigned idx = tid & 65535u;
        const float* s = (arr == 0) ? Wq : (arr == 1) ? Wk : Wv;
        unsigned char* d = (arr == 0) ? Wq8 : (arr == 1) ? Wk8 : Wv8;
        unsigned ww[4];
#pragma unroll
        for (int i = 0; i < 4; ++i) {
            f32x4 a = *reinterpret_cast<const f32x4*>(s + (size_t)idx * 16 + i * 4);
            ww[i] = cvt4fp8(a[0] * 64.f, a[1] * 64.f, a[2] * 64.f, a[3] * 64.f);
        }
        int o = (idx & 3) * 16;
        int s0 = (o < 32) ? 2 * o : 2 * (o - 32) + 8;
        unsigned char* base = d + (size_t)(idx >> 2) * 64;
        *reinterpret_cast<unsigned long long*>(base + s0) =
            (unsigned long long)ww[0] | ((unsigned long long)ww[1] << 32);
        *reinterpret_cast<unsigned long long*>(base + s0 + 16) =
            (unsigned long long)ww[2] | ((unsigned long long)ww[3] << 32);
    }
}

// --------------------- gemm256 (fp8 in, fp8 out; HW cvt epilogues) ----
// (unchanged from round 18, verified 138 us)
__global__ __launch_bounds__(512, 2) void gemm256(
    const unsigned char* __restrict__ A8, const unsigned char* __restrict__ Ah8,
    const unsigned char* __restrict__ W8, const unsigned char* __restrict__ Wq8,
    const float* __restrict__ bk, const float* __restrict__ bv, const float* __restrict__ bq,
    unsigned char* __restrict__ Cn, unsigned char* __restrict__ Vt, unsigned char* __restrict__ Qm)
{
    __shared__ __align__(16) char smemc[65536];

    int t = threadIdx.x, lane = t & 63, w = t >> 6, g = lane >> 4, lr = lane & 15;
    int wr = w >> 2, wcn = w & 3;
    int R0 = wr * 128, C0 = wcn * 64;

    int id = blockIdx.x;
    int m0, n0, trans = 0;
    const unsigned char *Ab_, *Wb_;
    const float* bias;
    unsigned char* Cout;
    if (id < 1024) {
        int xcd = id & 7, ord = id >> 3;
        int mt = xcd * 16 + ord / 8;
        int nt = ord % 8;
        m0 = mt * 256; n0 = nt * 256;
        Ab_ = A8; Wb_ = W8;
        if (nt < 4) { bias = bk; Cout = Cn; }
        else        { bias = bv; Cout = Vt; trans = 1; }
    } else {
        int id2 = id - 1024;
        int mt = id2 & 15, nt = id2 >> 4;
        m0 = mt * 256; n0 = nt * 256;
        Ab_ = Ah8; Wb_ = Wq8;
        bias = bq; Cout = Qm;
    }

    const unsigned char* Ap = Ab_ + (size_t)m0 * 1024;
    const unsigned char* Wp = Wb_ + (size_t)n0 * 1024;

    f32x4 acc[8][4];
#pragma unroll
    for (int i = 0; i < 8; ++i)
#pragma unroll
        for (int j = 0; j < 4; ++j) acc[i][j] = (f32x4)0.f;

    int schunk = (t & 3) ^ ((t >> 3) & 3);
    auto STAGE1 = [&](int slot, int kt, int q) {
        const unsigned char* P = (q < 2) ? Ap : Wp;
        char* ldsb = smemc + ((q < 2) ? 0 : 32768) + slot * 16384 + (q & 1) * 8192;
        int r = (q & 1) * 128 + (t >> 2);
        const char* gp = (const char*)(P + (size_t)r * 1024 + kt * 64 + schunk * 16);
        GLOAD16(gp, ldsb + (t >> 2) * 64 + (t & 3) * 16);
    };

    STAGE1(0, 0, 0); STAGE1(0, 0, 1); STAGE1(0, 0, 2); STAGE1(0, 0, 3);
    asm volatile("s_waitcnt vmcnt(0)" ::: "memory");
    __builtin_amdgcn_s_barrier();

    int xr = (lr >> 1) & 3;
    int slA = (g ^ xr) * 16;

    for (int kt = 0; kt < 16; ++kt) {
        const int cs = kt & 1;
        const char* Ab = smemc + cs * 16384;
        const char* Bb = smemc + 32768 + cs * 16384;
        i64x2 af[4], bf[4];

#pragma unroll
        for (int a = 0; a < 4; ++a) {
            int r = R0 + a * 16 + lr;
            af[a] = *reinterpret_cast<const i64x2*>(Ab + r * 64 + slA);
        }
#pragma unroll
        for (int ni = 0; ni < 4; ++ni) {
            int r = C0 + ni * 16 + lr;
            bf[ni] = *reinterpret_cast<const i64x2*>(Bb + r * 64 + slA);
        }
        if (kt < 15) { STAGE1(cs ^ 1, kt + 1, 0); STAGE1(cs ^ 1, kt + 1, 1); }
        __builtin_amdgcn_sched_barrier(0);
        __builtin_amdgcn_s_barrier();
        asm volatile("s_waitcnt lgkmcnt(0)" ::: "memory");
        __builtin_amdgcn_sched_barrier(0);
        __builtin_amdgcn_s_setprio(1);
#pragma unroll
        for (int a = 0; a < 4; ++a)
#pragma unroll
            for (int ni = 0; ni < 4; ++ni) {
                acc[a][ni] = __builtin_amdgcn_mfma_f32_16x16x32_fp8_fp8(
                    af[a][0], bf[ni][0], acc[a][ni], 0, 0, 0);
                acc[a][ni] = __builtin_amdgcn_mfma_f32_16x16x32_fp8_fp8(
                    af[a][1], bf[ni][1], acc[a][ni], 0, 0, 0);
            }
        __builtin_amdgcn_s_setprio(0);
        __builtin_amdgcn_sched_barrier(0);
        __builtin_amdgcn_s_barrier();

#pragma unroll
        for (int a = 0; a < 4; ++a) {
            int r = R0 + 64 + a * 16 + lr;
            af[a] = *reinterpret_cast<const i64x2*>(Ab + r * 64 + slA);
        }
        if (kt < 15) { STAGE1(cs ^ 1, kt + 1, 2); STAGE1(cs ^ 1, kt + 1, 3); }
        __builtin_amdgcn_sched_barrier(0);
        __builtin_amdgcn_s_barrier();
        asm volatile("s_waitcnt lgkmcnt(0)" ::: "memory");
        __builtin_amdgcn_sched_barrier(0);
        __builtin_amdgcn_s_setprio(1);
#pragma unroll
        for (int a = 0; a < 4; ++a)
#pragma unroll
            for (int ni = 0; ni < 4; ++ni) {
                acc[4 + a][ni] = __builtin_amdgcn_mfma_f32_16x16x32_fp8_fp8(
                    af[a][0], bf[ni][0], acc[4 + a][ni], 0, 0, 0);
                acc[4 + a][ni] = __builtin_amdgcn_mfma_f32_16x16x32_fp8_fp8(
                    af[a][1], bf[ni][1], acc[4 + a][ni], 0, 0, 0);
            }
        __builtin_amdgcn_s_setprio(0);
        asm volatile("s_waitcnt vmcnt(0)" ::: "memory");
        __builtin_amdgcn_sched_barrier(0);
        __builtin_amdgcn_s_barrier();
    }
    __syncthreads();

    const float SC = 0.015625f;   // 1/64 (W scale)
    unsigned char* CtS8 = (unsigned char*)smemc;   // [64][272] bytes
    if (!trans) {
#pragma unroll
        for (int ch = 0; ch < 4; ++ch) {
            if (ch) __syncthreads();
            if (wr == (ch >> 1)) {
                int ma = (ch & 1) * 4;
#pragma unroll
                for (int ni = 0; ni < 4; ++ni) {
                    int c = C0 + ni * 16 + lr;
                    float bvv = bias[n0 + c];
                    int cc = (c & ~63) + pi64(c & 63);
#pragma unroll
                    for (int a = 0; a < 4; ++a) {
                        unsigned wv = cvt4fp8(acc[ma + a][ni][0] * SC + bvv,
                                              acc[ma + a][ni][1] * SC + bvv,
                                              acc[ma + a][ni][2] * SC + bvv,
                                              acc[ma + a][ni][3] * SC + bvv);
#pragma unroll
                        for (int j = 0; j < 4; ++j)
                            CtS8[(a * 16 + g * 4 + j) * 272 + cc] =
                                (unsigned char)((wv >> (8 * j)) & 0xffu);
                    }
                }
            }
            __syncthreads();
#pragma unroll
            for (int it = 0; it < 2; ++it) {
                int u2 = it * 512 + t;
                int row = u2 >> 4, c16 = u2 & 15;
                *reinterpret_cast<f32x4*>(Cout + (size_t)(m0 + ch * 64 + row) * 1024 + n0 + c16 * 16) =
                    *reinterpret_cast<const f32x4*>(&CtS8[row * 272 + c16 * 16]);
            }
        }
    } else {
        int nt = n0 >> 8;
        int hbase = (nt - 4) * 2;
        int b = m0 >> 12, kv0 = m0 & 4095;
#pragma unroll
        for (int ch = 0; ch < 4; ++ch) {
            if (ch) __syncthreads();
            if (wcn == ch) {
#pragma unroll
                for (int ni = 0; ni < 4; ++ni) {
                    int dl = ni * 16 + lr;
                    float bvv = bias[(nt - 4) * 256 + ch * 64 + dl];
#pragma unroll
                    for (int mi = 0; mi < 8; ++mi) {
                        unsigned wv = cvt4fp8(acc[mi][ni][0] * SC + bvv,
                                              acc[mi][ni][1] * SC + bvv,
                                              acc[mi][ni][2] * SC + bvv,
                                              acc[mi][ni][3] * SC + bvv);
                        *reinterpret_cast<unsigned*>(
                            &CtS8[dl * 272 + R0 + mi * 16 + g * 4]) = wv;
                    }
                }
            }
            __syncthreads();
            int hh = hbase + (ch >> 1), dbase = (ch & 1) * 64;
            unsigned char* dst = Cout + ((size_t)(b * 8 + hh) * 128 + dbase) * 4096 + kv0;
#pragma unroll
            for (int it = 0; it < 2; ++it) {
                int u2 = it * 512 + t;
                int row = u2 >> 4, c16 = u2 & 15;
                *reinterpret_cast<f32x4*>(dst + (size_t)row * 4096 + c16 * 16) =
                    *reinterpret_cast<const f32x4*>(&CtS8[row * 272 + c16 * 16]);
            }
        }
    }
}

// ------------------------------ attention (fp8, triple-buffer, vmcnt(4)) ----
// Round-18 structure with 3 K/V buffers: stage chunk c+2 at chunk c, drain
// only the 4 oldest loads (vmcnt(4)) -> ~2 chunks of flight hides HBM/L2
// latency. lgkmcnt(0) before the barrier keeps the buffer-overwrite invariant.
__global__ __launch_bounds__(256, 2) void attn_kernel(
    const unsigned char* __restrict__ Qm8, const unsigned char* __restrict__ Km8,
    const unsigned char* __restrict__ Vt8, const float* __restrict__ hidden,
    float* __restrict__ out)
{
    __shared__ __align__(16) unsigned char Kl[3][64 * 128];   // 8 KB each
    __shared__ __align__(16) unsigned char Vt[3][128 * 64];   // 8 KB each
    __shared__ __align__(16) unsigned char Pl[64 * 64];       // 4 KB

    int t = threadIdx.x, lane = t & 63, w = t >> 6, g = lane >> 4, lr = lane & 15;
    int id = blockIdx.x;
    int swz = (id & 7) * 64 + (id >> 3);
    int qt = swz & 7, h = (swz >> 3) & 7, b = swz >> 6;

    i64x2 qf[2];
    {
        const unsigned char* qp = Qm8 + (size_t)(b * 512 + qt * 64 + w * 16 + lr) * 1024 + h * 128;
        qf[0] = *reinterpret_cast<const i64x2*>(qp + g * 16);
        qf[1] = *reinterpret_cast<const i64x2*>(qp + 64 + g * 16);
    }
    asm volatile("s_waitcnt vmcnt(0)" ::: "memory");

    float m2 = 0.f;
    float l = 0.f;
    f32x4 oacc[8];
#pragma unroll
    for (int nf = 0; nf < 8; ++nf) oacc[nf] = (f32x4)0.f;

    const float SCALE = 0.08838834764831845f;
    const float LOG2E = 1.4426950408889634f;
    const float K1 = SCALE * LOG2E;
    const float THR2 = 8.0f;

    size_t kbase = (size_t)b * 4096 * 1024 + h * 128;
    size_t vbase = ((size_t)(b * 8 + h)) * 128 * 4096;

    auto STAGE_K = [&](int buf, int c) {
        int kv0 = c * 64;
#pragma unroll
        for (int i = 0; i < 2; ++i) {
            int rb = w * 16 + i * 8;
            int row = rb + (lane >> 3);
            int cb = ((lane & 7) ^ (row & 7)) * 16;
            const unsigned char* gp = Km8 + kbase + (size_t)(kv0 + row) * 1024 + cb;
            GLOAD16(gp, &Kl[buf][rb * 128]);
        }
    };
    auto STAGE_V = [&](int buf, int c) {
        int kv0 = c * 64;
#pragma unroll
        for (int i = 0; i < 2; ++i) {
            int db = w * 32 + i * 16;
            int d = db + (lane >> 2);
            int cb = ((lane & 3) ^ ((d >> 1) & 3)) * 16;
            const unsigned char* gp = Vt8 + vbase + (size_t)d * 4096 + kv0 + cb;
            GLOAD16(gp, &Vt[buf][db * 64]);
        }
    };

    STAGE_K(0, 0); STAGE_V(0, 0);
    STAGE_K(1, 1); STAGE_V(1, 1);

    int rsw8 = (lr & 7) << 3;

    for (int c = 0; c < 64; ++c) {
        int cur = c % 3;
        // chunk c's 4 loads are the oldest; allow chunk c+1's 4 to stay in flight
        if (c < 63) asm volatile("s_waitcnt vmcnt(4) lgkmcnt(0)" ::: "memory");
        else        asm volatile("s_waitcnt vmcnt(0) lgkmcnt(0)" ::: "memory");
        __builtin_amdgcn_sched_barrier(0);
        __builtin_amdgcn_s_barrier();
        if (c + 2 < 64) {
            int nb = (c + 2) % 3;
            STAGE_K(nb, c + 2); STAGE_V(nb, c + 2);
        }

        const unsigned char* Kb = &Kl[cur][0];
        const unsigned char* Vb = &Vt[cur][0];

        f32x4 sacc[4];
#pragma unroll
        for (int nf = 0; nf < 4; ++nf) sacc[nf] = (f32x4)0.f;
#pragma unroll
        for (int kk2 = 0; kk2 < 2; ++kk2) {
            i64x2 kf[4];
#pragma unroll
            for (int nf = 0; nf < 4; ++nf) {
                int row = nf * 16 + lr;
                kf[nf] = *reinterpret_cast<const i64x2*>(
                    &Kb[row * 128 + ((kk2 * 64 + g * 16) ^ ((row & 7) << 4))]);
            }
            __builtin_amdgcn_s_setprio(1);
#pragma unroll
            for (int nf = 0; nf < 4; ++nf) {
                sacc[nf] = __builtin_amdgcn_mfma_f32_16x16x32_fp8_fp8(kf[nf][0], qf[kk2][0], sacc[nf], 0, 0, 0);
                sacc[nf] = __builtin_amdgcn_mfma_f32_16x16x32_fp8_fp8(kf[nf][1], qf[kk2][1], sacc[nf], 0, 0, 0);
            }
            __builtin_amdgcn_s_setprio(0);
        }

        float smax = sacc[0][0];
#pragma unroll
        for (int nf = 0; nf < 4; ++nf)
#pragma unroll
            for (int j = 0; j < 4; ++j) smax = fmaxf(smax, sacc[nf][j]);
        float s2max = smax * K1;
        if (!__all(s2max <= m2 + THR2)) {
            float rm = s2max;
            rm = fmaxf(rm, __shfl_xor(rm, 16));
            rm = fmaxf(rm, __shfl_xor(rm, 32));
            float m2n = fmaxf(m2, rm);
            float corr = exp2f(m2 - m2n);
            l *= corr;
            m2 = m2n;
#pragma unroll
            for (int j = 0; j < 4; ++j) {
                float cj = __shfl(corr, g * 4 + j);
#pragma unroll
                for (int nf = 0; nf < 8; ++nf) oacc[nf][j] *= cj;
            }
        }
        int prow = w * 16 + lr;
#pragma unroll
        for (int nf = 0; nf < 4; ++nf) {
            float p0 = exp2f(sacc[nf][0] * K1 - m2);
            float p1 = exp2f(sacc[nf][1] * K1 - m2);
            float p2 = exp2f(sacc[nf][2] * K1 - m2);
            float p3 = exp2f(sacc[nf][3] * K1 - m2);
            l += (p0 + p1) + (p2 + p3);
            unsigned pk = cvt4fp8(p0, p1, p2, p3);
            int pos = nf * 16 + g * 4;
            *reinterpret_cast<unsigned*>(
                &Pl[prow * 64 + ((pos & 0x38) ^ rsw8) + (pos & 7)]) = pk;
        }
        asm volatile("s_waitcnt lgkmcnt(0)" ::: "memory");
        __builtin_amdgcn_sched_barrier(0);

#pragma unroll
        for (int kp = 0; kp < 2; ++kp) {
            long pa = *reinterpret_cast<const long*>(
                &Pl[prow * 64 + ((kp * 32 + g * 8) ^ rsw8)]);
#pragma unroll
            for (int nf = 0; nf < 8; ++nf) {
                int d = nf * 16 + lr;
                long vb = *reinterpret_cast<const long*>(
                    &Vb[d * 64 + ((kp * 32 + g * 8) ^ ((d & 6) << 3))]);
                oacc[nf] = __builtin_amdgcn_mfma_f32_16x16x32_fp8_fp8(pa, vb, oacc[nf], 0, 0, 0);
            }
        }
    }

    l += __shfl_xor(l, 16);
    l += __shfl_xor(l, 32);
#pragma unroll
    for (int j = 0; j < 4; ++j) {
        float lj = __shfl(l, g * 4 + j);
        float inv = 1.f / lj;
        int q = qt * 64 + w * 16 + g * 4 + j;
        size_t base = (size_t)(b * 512 + q) * 1024 + h * 128;
#pragma unroll
        for (int nf = 0; nf < 8; ++nf) {
            int d = nf * 16 + lr;
            out[base + d] = hidden[base + d] + oacc[nf][j] * inv;
        }
    }
}

// ---------------------------------------------------------------- host ----
extern "C" void kernel_launch(void* const* d_in, const int* in_sizes, int n_in,
                              void* d_out, int out_size, void* d_ws, size_t ws_size,
                              hipStream_t stream) {
    const float* hidden = (const float*)d_in[0];
    const float* inputs = (const float*)d_in[1];
    const float* ln1w   = (const float*)d_in[2];
    const float* ln1b   = (const float*)d_in[3];
    const float* ln2w   = (const float*)d_in[4];
    const float* ln2b   = (const float*)d_in[5];
    const float* Wq     = (const float*)d_in[6];
    const float* bq     = (const float*)d_in[7];
    const float* Wk     = (const float*)d_in[8];
    const float* bk     = (const float*)d_in[9];
    const float* Wv     = (const float*)d_in[10];
    const float* bv     = (const float*)d_in[11];
    float* out = (float*)d_out;
    char* ws = (char*)d_ws;

    unsigned char* LNh8 = (unsigned char*)ws;          // 4096x1024 fp8
    unsigned char* LNx8 = LNh8 + 4194304;              // 32768x1024 fp8
    unsigned char* Wq8  = LNx8 + 33554432;
    unsigned char* Wk8  = Wq8 + 1048576;
    unsigned char* Wv8  = Wk8 + 1048576;
    unsigned char* Qm8  = Wv8 + 1048576;               // 4096x1024 fp8 (pi'd d)
    unsigned char* Km8  = Qm8 + 4194304;               // 32768x1024 fp8 (pi'd d)
    unsigned char* Vt8  = Km8 + 33554432;              // [b][h][128 d][4096 kv] fp8

    prep<<<dim3(9984), dim3(256), 0, stream>>>(
        hidden, inputs, ln1w, ln1b, ln2w, ln2b, Wq, Wk, Wv, LNh8, LNx8, Wq8, Wk8, Wv8);
    gemm256<<<dim3(1088), dim3(512), 0, stream>>>(
        LNx8, LNh8, Wk8, Wq8, bk, bv, bq, Km8, Vt8, Qm8);
    attn_kernel<<<dim3(512), dim3(256), 0, stream>>>(Qm8, Km8, Vt8, hidden, out);
}

// Round 20
// 260.356 us; speedup vs baseline: 1.1538x; 1.0031x over previous
//
#include <hip/hip_runtime.h>

typedef __attribute__((ext_vector_type(8))) short short8;
typedef __attribute__((ext_vector_type(4))) float f32x4;
typedef __attribute__((ext_vector_type(2))) long i64x2;

#define DEV __device__ __forceinline__

DEV unsigned short f2bf(float f) {
    unsigned int u = __builtin_bit_cast(unsigned int, f);
    u += 0x7fffu + ((u >> 16) & 1u);
    return (unsigned short)(u >> 16);
}

// 4 floats -> 4 packed OCP e4m3 bytes via v_cvt_pk_fp8_f32 (HW, saturating)
DEV unsigned cvt4fp8(float a, float b, float c, float d) {
    int w = __builtin_amdgcn_cvt_pk_fp8_f32(a, b, 0, false);
    w = __builtin_amdgcn_cvt_pk_fp8_f32(c, d, w, true);
    return (unsigned)w;
}

#define GLOAD16(gp, lp)                                                        \
    __builtin_amdgcn_global_load_lds(                                          \
        (const __attribute__((address_space(1))) void*)(gp),                   \
        (__attribute__((address_space(3))) void*)(lp), 16, 0, 0)

// pi within a 64-block: stored[16j+i]=log[8j+i], stored[16j+8+i]=log[32+8j+i]
DEV int pi64(int o) {
    return (o < 32) ? ((o >> 3) * 16 + (o & 7)) : (((o - 32) >> 3) * 16 + 8 + (o & 7));
}

// ---------------------------------------------------- prep (LN+convert, fp8) ----
__global__ __launch_bounds__(256) void prep(
    const float* __restrict__ hidden, const float* __restrict__ inputs,
    const float* __restrict__ ln1w, const float* __restrict__ ln1b,
    const float* __restrict__ ln2w, const float* __restrict__ ln2b,
    const float* __restrict__ Wq, const float* __restrict__ Wk, const float* __restrict__ Wv,
    unsigned char* __restrict__ LNh8, unsigned char* __restrict__ LNx8,
    unsigned char* __restrict__ Wq8, unsigned char* __restrict__ Wk8, unsigned char* __restrict__ Wv8)
{
    if (blockIdx.x < 9216) {
        int row = blockIdx.x * 4 + (threadIdx.x >> 6);
        int lane = threadIdx.x & 63;
        const float *src, *wp, *bp; unsigned char* dst;
        if (row < 4096) { src = hidden + (size_t)row * 1024; wp = ln1w; bp = ln1b; dst = LNh8 + (size_t)row * 1024; }
        else { int r = row - 4096; src = inputs + (size_t)r * 1024; wp = ln2w; bp = ln2b; dst = LNx8 + (size_t)r * 1024; }

        f32x4 v[4];
        float s = 0.f, ss = 0.f;
#pragma unroll
        for (int i = 0; i < 4; ++i) {
            v[i] = *reinterpret_cast<const f32x4*>(src + lane * 16 + i * 4);
#pragma unroll
            for (int j = 0; j < 4; ++j) { s += v[i][j]; ss += v[i][j] * v[i][j]; }
        }
#pragma unroll
        for (int off = 32; off >= 1; off >>= 1) { s += __shfl_xor(s, off); ss += __shfl_xor(ss, off); }
        float mu = s * (1.f / 1024.f);
        float var = fmaxf(ss * (1.f / 1024.f) - mu * mu, 0.f);
        float rs = rsqrtf(var + 1e-5f);

        unsigned ww[4];
#pragma unroll
        for (int i = 0; i < 4; ++i) {
            f32x4 wv = *reinterpret_cast<const f32x4*>(wp + lane * 16 + i * 4);
            f32x4 bv = *reinterpret_cast<const f32x4*>(bp + lane * 16 + i * 4);
            f32x4 o;
#pragma unroll
            for (int j = 0; j < 4; ++j) o[j] = (v[i][j] - mu) * rs * wv[j] + bv[j];
            ww[i] = cvt4fp8(o[0], o[1], o[2], o[3]);
        }
        int o = (lane * 16) & 63;
        int s0 = (o < 32) ? 2 * o : 2 * (o - 32) + 8;
        unsigned char* base = dst + (lane >> 2) * 64;
        *reinterpret_cast<unsigned long long*>(base + s0) =
            (unsigned long long)ww[0] | ((unsigned long long)ww[1] << 32);
        *reinterpret_cast<unsigned long long*>(base + s0 + 16) =
            (unsigned long long)ww[2] | ((unsigned long long)ww[3] << 32);
    } else {
        unsigned tid = (blockIdx.x - 9216) * 256 + threadIdx.x;
        int arr = tid >> 16;
        unsigned idx = tid & 65535u;
        const float* s = (arr == 0) ? Wq : (arr == 1) ? Wk : Wv;
        unsigned char* d = (arr == 0) ? Wq8 : (arr == 1) ? Wk8 : Wv8;
        unsigned ww[4];
#pragma unroll
        for (int i = 0; i < 4; ++i) {
            f32x4 a = *reinterpret_cast<const f32x4*>(s + (size_t)idx * 16 + i * 4);
            ww[i] = cvt4fp8(a[0] * 64.f, a[1] * 64.f, a[2] * 64.f, a[3] * 64.f);
        }
        int o = (idx & 3) * 16;
        int s0 = (o < 32) ? 2 * o : 2 * (o - 32) + 8;
        unsigned char* base = d + (size_t)(idx >> 2) * 64;
        *reinterpret_cast<unsigned long long*>(base + s0) =
            (unsigned long long)ww[0] | ((unsigned long long)ww[1] << 32);
        *reinterpret_cast<unsigned long long*>(base + s0 + 16) =
            (unsigned long long)ww[2] | ((unsigned long long)ww[3] << 32);
    }
}

// --------------------- gemm256 (fp8 in, fp8 out; HW cvt epilogues) ----
// (unchanged from round 18/19, verified 138 us)
__global__ __launch_bounds__(512, 2) void gemm256(
    const unsigned char* __restrict__ A8, const unsigned char* __restrict__ Ah8,
    const unsigned char* __restrict__ W8, const unsigned char* __restrict__ Wq8,
    const float* __restrict__ bk, const float* __restrict__ bv, const float* __restrict__ bq,
    unsigned char* __restrict__ Cn, unsigned char* __restrict__ Vt, unsigned char* __restrict__ Qm)
{
    __shared__ __align__(16) char smemc[65536];

    int t = threadIdx.x, lane = t & 63, w = t >> 6, g = lane >> 4, lr = lane & 15;
    int wr = w >> 2, wcn = w & 3;
    int R0 = wr * 128, C0 = wcn * 64;

    int id = blockIdx.x;
    int m0, n0, trans = 0;
    const unsigned char *Ab_, *Wb_;
    const float* bias;
    unsigned char* Cout;
    if (id < 1024) {
        int xcd = id & 7, ord = id >> 3;
        int mt = xcd * 16 + ord / 8;
        int nt = ord % 8;
        m0 = mt * 256; n0 = nt * 256;
        Ab_ = A8; Wb_ = W8;
        if (nt < 4) { bias = bk; Cout = Cn; }
        else        { bias = bv; Cout = Vt; trans = 1; }
    } else {
        int id2 = id - 1024;
        int mt = id2 & 15, nt = id2 >> 4;
        m0 = mt * 256; n0 = nt * 256;
        Ab_ = Ah8; Wb_ = Wq8;
        bias = bq; Cout = Qm;
    }

    const unsigned char* Ap = Ab_ + (size_t)m0 * 1024;
    const unsigned char* Wp = Wb_ + (size_t)n0 * 1024;

    f32x4 acc[8][4];
#pragma unroll
    for (int i = 0; i < 8; ++i)
#pragma unroll
        for (int j = 0; j < 4; ++j) acc[i][j] = (f32x4)0.f;

    int schunk = (t & 3) ^ ((t >> 3) & 3);
    auto STAGE1 = [&](int slot, int kt, int q) {
        const unsigned char* P = (q < 2) ? Ap : Wp;
        char* ldsb = smemc + ((q < 2) ? 0 : 32768) + slot * 16384 + (q & 1) * 8192;
        int r = (q & 1) * 128 + (t >> 2);
        const char* gp = (const char*)(P + (size_t)r * 1024 + kt * 64 + schunk * 16);
        GLOAD16(gp, ldsb + (t >> 2) * 64 + (t & 3) * 16);
    };

    STAGE1(0, 0, 0); STAGE1(0, 0, 1); STAGE1(0, 0, 2); STAGE1(0, 0, 3);
    asm volatile("s_waitcnt vmcnt(0)" ::: "memory");
    __builtin_amdgcn_s_barrier();

    int xr = (lr >> 1) & 3;
    int slA = (g ^ xr) * 16;

    for (int kt = 0; kt < 16; ++kt) {
        const int cs = kt & 1;
        const char* Ab = smemc + cs * 16384;
        const char* Bb = smemc + 32768 + cs * 16384;
        i64x2 af[4], bf[4];

#pragma unroll
        for (int a = 0; a < 4; ++a) {
            int r = R0 + a * 16 + lr;
            af[a] = *reinterpret_cast<const i64x2*>(Ab + r * 64 + slA);
        }
#pragma unroll
        for (int ni = 0; ni < 4; ++ni) {
            int r = C0 + ni * 16 + lr;
            bf[ni] = *reinterpret_cast<const i64x2*>(Bb + r * 64 + slA);
        }
        if (kt < 15) { STAGE1(cs ^ 1, kt + 1, 0); STAGE1(cs ^ 1, kt + 1, 1); }
        __builtin_amdgcn_sched_barrier(0);
        __builtin_amdgcn_s_barrier();
        asm volatile("s_waitcnt lgkmcnt(0)" ::: "memory");
        __builtin_amdgcn_sched_barrier(0);
        __builtin_amdgcn_s_setprio(1);
#pragma unroll
        for (int a = 0; a < 4; ++a)
#pragma unroll
            for (int ni = 0; ni < 4; ++ni) {
                acc[a][ni] = __builtin_amdgcn_mfma_f32_16x16x32_fp8_fp8(
                    af[a][0], bf[ni][0], acc[a][ni], 0, 0, 0);
                acc[a][ni] = __builtin_amdgcn_mfma_f32_16x16x32_fp8_fp8(
                    af[a][1], bf[ni][1], acc[a][ni], 0, 0, 0);
            }
        __builtin_amdgcn_s_setprio(0);
        __builtin_amdgcn_sched_barrier(0);
        __builtin_amdgcn_s_barrier();

#pragma unroll
        for (int a = 0; a < 4; ++a) {
            int r = R0 + 64 + a * 16 + lr;
            af[a] = *reinterpret_cast<const i64x2*>(Ab + r * 64 + slA);
        }
        if (kt < 15) { STAGE1(cs ^ 1, kt + 1, 2); STAGE1(cs ^ 1, kt + 1, 3); }
        __builtin_amdgcn_sched_barrier(0);
        __builtin_amdgcn_s_barrier();
        asm volatile("s_waitcnt lgkmcnt(0)" ::: "memory");
        __builtin_amdgcn_sched_barrier(0);
        __builtin_amdgcn_s_setprio(1);
#pragma unroll
        for (int a = 0; a < 4; ++a)
#pragma unroll
            for (int ni = 0; ni < 4; ++ni) {
                acc[4 + a][ni] = __builtin_amdgcn_mfma_f32_16x16x32_fp8_fp8(
                    af[a][0], bf[ni][0], acc[4 + a][ni], 0, 0, 0);
                acc[4 + a][ni] = __builtin_amdgcn_mfma_f32_16x16x32_fp8_fp8(
                    af[a][1], bf[ni][1], acc[4 + a][ni], 0, 0, 0);
            }
        __builtin_amdgcn_s_setprio(0);
        asm volatile("s_waitcnt vmcnt(0)" ::: "memory");
        __builtin_amdgcn_sched_barrier(0);
        __builtin_amdgcn_s_barrier();
    }
    __syncthreads();

    const float SC = 0.015625f;   // 1/64 (W scale)
    unsigned char* CtS8 = (unsigned char*)smemc;   // [64][272] bytes
    if (!trans) {
#pragma unroll
        for (int ch = 0; ch < 4; ++ch) {
            if (ch) __syncthreads();
            if (wr == (ch >> 1)) {
                int ma = (ch & 1) * 4;
#pragma unroll
                for (int ni = 0; ni < 4; ++ni) {
                    int c = C0 + ni * 16 + lr;
                    float bvv = bias[n0 + c];
                    int cc = (c & ~63) + pi64(c & 63);
#pragma unroll
                    for (int a = 0; a < 4; ++a) {
                        unsigned wv = cvt4fp8(acc[ma + a][ni][0] * SC + bvv,
                                              acc[ma + a][ni][1] * SC + bvv,
                                              acc[ma + a][ni][2] * SC + bvv,
                                              acc[ma + a][ni][3] * SC + bvv);
#pragma unroll
                        for (int j = 0; j < 4; ++j)
                            CtS8[(a * 16 + g * 4 + j) * 272 + cc] =
                                (unsigned char)((wv >> (8 * j)) & 0xffu);
                    }
                }
            }
            __syncthreads();
#pragma unroll
            for (int it = 0; it < 2; ++it) {
                int u2 = it * 512 + t;
                int row = u2 >> 4, c16 = u2 & 15;
                *reinterpret_cast<f32x4*>(Cout + (size_t)(m0 + ch * 64 + row) * 1024 + n0 + c16 * 16) =
                    *reinterpret_cast<const f32x4*>(&CtS8[row * 272 + c16 * 16]);
            }
        }
    } else {
        int nt = n0 >> 8;
        int hbase = (nt - 4) * 2;
        int b = m0 >> 12, kv0 = m0 & 4095;
#pragma unroll
        for (int ch = 0; ch < 4; ++ch) {
            if (ch) __syncthreads();
            if (wcn == ch) {
#pragma unroll
                for (int ni = 0; ni < 4; ++ni) {
                    int dl = ni * 16 + lr;
                    float bvv = bias[(nt - 4) * 256 + ch * 64 + dl];
#pragma unroll
                    for (int mi = 0; mi < 8; ++mi) {
                        unsigned wv = cvt4fp8(acc[mi][ni][0] * SC + bvv,
                                              acc[mi][ni][1] * SC + bvv,
                                              acc[mi][ni][2] * SC + bvv,
                                              acc[mi][ni][3] * SC + bvv);
                        *reinterpret_cast<unsigned*>(
                            &CtS8[dl * 272 + R0 + mi * 16 + g * 4]) = wv;
                    }
                }
            }
            __syncthreads();
            int hh = hbase + (ch >> 1), dbase = (ch & 1) * 64;
            unsigned char* dst = Cout + ((size_t)(b * 8 + hh) * 128 + dbase) * 4096 + kv0;
#pragma unroll
            for (int it = 0; it < 2; ++it) {
                int u2 = it * 512 + t;
                int row = u2 >> 4, c16 = u2 & 15;
                *reinterpret_cast<f32x4*>(dst + (size_t)row * 4096 + c16 * 16) =
                    *reinterpret_cast<const f32x4*>(&CtS8[row * 272 + c16 * 16]);
            }
        }
    }
}

// ------------------------------ attention (fp8, KVBLK=128, dbuf) ----
// 32 chunks of 128 kv: per-chunk fixed costs (barrier, drain, guard, stage
// burst) halve vs KVBLK=64. LDS 72KB (2 blk/CU). P: 8B-granule XOR ^lr;
// V: 16B-granule XOR ^(d&7) (source pre-swizzled, same involution).
__global__ __launch_bounds__(256, 2) void attn_kernel(
    const unsigned char* __restrict__ Qm8, const unsigned char* __restrict__ Km8,
    const unsigned char* __restrict__ Vt8, const float* __restrict__ hidden,
    float* __restrict__ out)
{
    __shared__ __align__(16) unsigned char Kl[2][128 * 128];   // 16 KB each
    __shared__ __align__(16) unsigned char Vt[2][128 * 128];   // 16 KB each
    __shared__ __align__(16) unsigned char Pl[64 * 128];       //  8 KB

    int t = threadIdx.x, lane = t & 63, w = t >> 6, g = lane >> 4, lr = lane & 15;
    int id = blockIdx.x;
    int swz = (id & 7) * 64 + (id >> 3);
    int qt = swz & 7, h = (swz >> 3) & 7, b = swz >> 6;

    i64x2 qf[2];
    {
        const unsigned char* qp = Qm8 + (size_t)(b * 512 + qt * 64 + w * 16 + lr) * 1024 + h * 128;
        qf[0] = *reinterpret_cast<const i64x2*>(qp + g * 16);
        qf[1] = *reinterpret_cast<const i64x2*>(qp + 64 + g * 16);
    }
    asm volatile("s_waitcnt vmcnt(0)" ::: "memory");

    float m2 = 0.f;
    float l = 0.f;
    f32x4 oacc[8];
#pragma unroll
    for (int nf = 0; nf < 8; ++nf) oacc[nf] = (f32x4)0.f;

    const float SCALE = 0.08838834764831845f;
    const float LOG2E = 1.4426950408889634f;
    const float K1 = SCALE * LOG2E;
    const float THR2 = 8.0f;

    size_t kbase = (size_t)b * 4096 * 1024 + h * 128;
    size_t vbase = ((size_t)(b * 8 + h)) * 128 * 4096;

    auto STAGE_K = [&](int buf, int c) {
        int kv0 = c * 128;
#pragma unroll
        for (int i = 0; i < 4; ++i) {
            int rb = w * 32 + i * 8;
            int row = rb + (lane >> 3);
            int cb = ((lane & 7) ^ (row & 7)) * 16;
            const unsigned char* gp = Km8 + kbase + (size_t)(kv0 + row) * 1024 + cb;
            GLOAD16(gp, &Kl[buf][rb * 128]);
        }
    };
    auto STAGE_V = [&](int buf, int c) {
        int kv0 = c * 128;
#pragma unroll
        for (int i = 0; i < 4; ++i) {
            int db = w * 32 + i * 8;
            int d = db + (lane >> 3);
            int cb = ((lane & 7) ^ (d & 7)) * 16;
            const unsigned char* gp = Vt8 + vbase + (size_t)d * 4096 + kv0 + cb;
            GLOAD16(gp, &Vt[buf][db * 128]);
        }
    };

    STAGE_K(0, 0); STAGE_V(0, 0);

    for (int c = 0; c < 32; ++c) {
        int cur = c & 1;
        asm volatile("s_waitcnt vmcnt(0) lgkmcnt(0)" ::: "memory");
        __builtin_amdgcn_sched_barrier(0);
        __builtin_amdgcn_s_barrier();
        if (c < 31) { STAGE_K(cur ^ 1, c + 1); STAGE_V(cur ^ 1, c + 1); }

        const unsigned char* Kb = &Kl[cur][0];
        const unsigned char* Vb = &Vt[cur][0];

        // S^T = K * Q^T : sacc[nf][j] = S[q=lr][kv = nf*16 + g*4 + j], nf 0..7
        f32x4 sacc[8];
#pragma unroll
        for (int nf = 0; nf < 8; ++nf) sacc[nf] = (f32x4)0.f;
#pragma unroll
        for (int kk2 = 0; kk2 < 2; ++kk2) {
#pragma unroll
            for (int hh = 0; hh < 2; ++hh) {
                i64x2 kf[4];
#pragma unroll
                for (int n = 0; n < 4; ++n) {
                    int row = (hh * 4 + n) * 16 + lr;
                    kf[n] = *reinterpret_cast<const i64x2*>(
                        &Kb[row * 128 + ((kk2 * 64 + g * 16) ^ ((row & 7) << 4))]);
                }
                __builtin_amdgcn_s_setprio(1);
#pragma unroll
                for (int n = 0; n < 4; ++n) {
                    sacc[hh * 4 + n] = __builtin_amdgcn_mfma_f32_16x16x32_fp8_fp8(
                        kf[n][0], qf[kk2][0], sacc[hh * 4 + n], 0, 0, 0);
                    sacc[hh * 4 + n] = __builtin_amdgcn_mfma_f32_16x16x32_fp8_fp8(
                        kf[n][1], qf[kk2][1], sacc[hh * 4 + n], 0, 0, 0);
                }
                __builtin_amdgcn_s_setprio(0);
            }
        }

        float smax = sacc[0][0];
#pragma unroll
        for (int nf = 0; nf < 8; ++nf)
#pragma unroll
            for (int j = 0; j < 4; ++j) smax = fmaxf(smax, sacc[nf][j]);
        float s2max = smax * K1;
        if (!__all(s2max <= m2 + THR2)) {
            float rm = s2max;
            rm = fmaxf(rm, __shfl_xor(rm, 16));
            rm = fmaxf(rm, __shfl_xor(rm, 32));
            float m2n = fmaxf(m2, rm);
            float corr = exp2f(m2 - m2n);
            l *= corr;
            m2 = m2n;
#pragma unroll
            for (int j = 0; j < 4; ++j) {
                float cj = __shfl(corr, g * 4 + j);
#pragma unroll
                for (int nf = 0; nf < 8; ++nf) oacc[nf][j] *= cj;
            }
        }
        int prow = w * 16 + lr;
#pragma unroll
        for (int nf = 0; nf < 8; ++nf) {
            float p0 = exp2f(sacc[nf][0] * K1 - m2);
            float p1 = exp2f(sacc[nf][1] * K1 - m2);
            float p2 = exp2f(sacc[nf][2] * K1 - m2);
            float p3 = exp2f(sacc[nf][3] * K1 - m2);
            l += (p0 + p1) + (p2 + p3);
            unsigned pk = cvt4fp8(p0, p1, p2, p3);
            // 8B granule (nf*2 + (g>>1)) ^ lr, sub-offset (g&1)*4
            *reinterpret_cast<unsigned*>(
                &Pl[prow * 128 + (((nf * 2 + (g >> 1)) ^ lr) << 3) + (g & 1) * 4]) = pk;
        }
        asm volatile("s_waitcnt lgkmcnt(0)" ::: "memory");
        __builtin_amdgcn_sched_barrier(0);

        // O += P * V^T : kp 0..3 over the 128-kv chunk
#pragma unroll
        for (int kp = 0; kp < 4; ++kp) {
            long pa = *reinterpret_cast<const long*>(
                &Pl[prow * 128 + (((kp * 4 + g) ^ lr) << 3)]);
#pragma unroll
            for (int nf = 0; nf < 8; ++nf) {
                int d = nf * 16 + lr;
                long vb = *reinterpret_cast<const long*>(
                    &Vb[d * 128 + (((kp * 2 + (g >> 1)) ^ (d & 7)) << 4) + (g & 1) * 8]);
                oacc[nf] = __builtin_amdgcn_mfma_f32_16x16x32_fp8_fp8(pa, vb, oacc[nf], 0, 0, 0);
            }
        }
    }

    l += __shfl_xor(l, 16);
    l += __shfl_xor(l, 32);
#pragma unroll
    for (int j = 0; j < 4; ++j) {
        float lj = __shfl(l, g * 4 + j);
        float inv = 1.f / lj;
        int q = qt * 64 + w * 16 + g * 4 + j;
        size_t base = (size_t)(b * 512 + q) * 1024 + h * 128;
#pragma unroll
        for (int nf = 0; nf < 8; ++nf) {
            int d = nf * 16 + lr;
            out[base + d] = hidden[base + d] + oacc[nf][j] * inv;
        }
    }
}

// ---------------------------------------------------------------- host ----
extern "C" void kernel_launch(void* const* d_in, const int* in_sizes, int n_in,
                              void* d_out, int out_size, void* d_ws, size_t ws_size,
                              hipStream_t stream) {
    const float* hidden = (const float*)d_in[0];
    const float* inputs = (const float*)d_in[1];
    const float* ln1w   = (const float*)d_in[2];
    const float* ln1b   = (const float*)d_in[3];
    const float* ln2w   = (const float*)d_in[4];
    const float* ln2b   = (const float*)d_in[5];
    const float* Wq     = (const float*)d_in[6];
    const float* bq     = (const float*)d_in[7];
    const float* Wk     = (const float*)d_in[8];
    const float* bk     = (const float*)d_in[9];
    const float* Wv     = (const float*)d_in[10];
    const float* bv     = (const float*)d_in[11];
    float* out = (float*)d_out;
    char* ws = (char*)d_ws;

    unsigned char* LNh8 = (unsigned char*)ws;          // 4096x1024 fp8
    unsigned char* LNx8 = LNh8 + 4194304;              // 32768x1024 fp8
    unsigned char* Wq8  = LNx8 + 33554432;
    unsigned char* Wk8  = Wq8 + 1048576;
    unsigned char* Wv8  = Wk8 + 1048576;
    unsigned char* Qm8  = Wv8 + 1048576;               // 4096x1024 fp8 (pi'd d)
    unsigned char* Km8  = Qm8 + 4194304;               // 32768x1024 fp8 (pi'd d)
    unsigned char* Vt8  = Km8 + 33554432;              // [b][h][128 d][4096 kv] fp8

    prep<<<dim3(9984), dim3(256), 0, stream>>>(
        hidden, inputs, ln1w, ln1b, ln2w, ln2b, Wq, Wk, Wv, LNh8, LNx8, Wq8, Wk8, Wv8);
    gemm256<<<dim3(1088), dim3(512), 0, stream>>>(
        LNx8, LNh8, Wk8, Wq8, bk, bv, bq, Km8, Vt8, Qm8);
    attn_kernel<<<dim3(512), dim3(256), 0, stream>>>(Qm8, Km8, Vt8, hidden, out);
}